// Round 1
// baseline (182.003 us; speedup 1.0000x reference)
//
#include <hip/hip_runtime.h>
#include <hip/hip_bf16.h>

typedef unsigned short u16;
typedef __bf16 bf16x8 __attribute__((ext_vector_type(8)));
typedef __bf16 bf16x4 __attribute__((ext_vector_type(4)));
typedef float f32x4 __attribute__((ext_vector_type(4)));
typedef unsigned int uint32x2 __attribute__((ext_vector_type(2)));

#define MFMA16(a, b, c) __builtin_amdgcn_mfma_f32_16x16x32_bf16(a, b, c, 0, 0, 0)

// ---------------------------------------------------------------------------
// Projections: fkeys/fvals/hkeys = W @ src + b, output bf16.
//   fkT[b][l][64]  (transposed: k contiguous -> A-operand 16B lane loads)
//   hkT[b][q][64]  (transposed: k contiguous -> B-operand 16B lane loads)
//   fv [b][64][l]  (natural: l contiguous -> A-operand 16B lane loads for PV)
// grid: (L/256, B, 6)  z = proj*2 + khalf  (32 k per block)
// ---------------------------------------------------------------------------
__global__ __launch_bounds__(256) void proj_kernel(
    const float* __restrict__ field, const float* __restrict__ query,
    const float* __restrict__ Wfk, const float* __restrict__ bfk,
    const float* __restrict__ Wfv, const float* __restrict__ bfv,
    const float* __restrict__ Wqk, const float* __restrict__ bqk,
    u16* __restrict__ fkT, u16* __restrict__ fvp, u16* __restrict__ hkT) {
  const int l = blockIdx.x * 256 + threadIdx.x;
  const int b = blockIdx.y;
  const int z = blockIdx.z;
  const int proj = z >> 1;        // 0=fk, 1=fv, 2=hk
  const int k0 = (z & 1) * 32;

  const float* src  = (proj == 2) ? query : field;
  const float* W    = (proj == 0) ? Wfk : (proj == 1) ? Wfv : Wqk;
  const float* bias = (proj == 0) ? bfk : (proj == 1) ? bfv : bqk;

  // pull the whole channel column into registers (128 VGPRs)
  float x[128];
  const float* sp = src + (size_t)b * 128 * 4096 + l;
#pragma unroll
  for (int f = 0; f < 128; ++f) x[f] = sp[(size_t)f * 4096];

  float acc[32];
#pragma unroll
  for (int i = 0; i < 32; ++i) acc[i] = bias[k0 + i];

  // W rows are wave-uniform -> scalar loads; 4096 v_fmac per thread
  for (int i = 0; i < 32; ++i) {
    const float* wr = W + (size_t)(k0 + i) * 128;
    float a = acc[i];
#pragma unroll
    for (int f = 0; f < 128; ++f) a = fmaf(wr[f], x[f], a);
    acc[i] = a;
  }

  if (proj == 1) {
#pragma unroll
    for (int i = 0; i < 32; ++i) {
      __bf16 h = (__bf16)acc[i];
      fvp[((size_t)(b * 64 + k0 + i)) * 4096 + l] = __builtin_bit_cast(u16, h);
    }
  } else {
    u16* dst = ((proj == 0) ? fkT : hkT) + ((size_t)(b * 4096 + l)) * 64 + k0;
#pragma unroll
    for (int g = 0; g < 4; ++g) {
      bf16x8 o;
#pragma unroll
      for (int j = 0; j < 8; ++j) o[j] = (__bf16)acc[g * 8 + j];
      *reinterpret_cast<bf16x8*>(dst + g * 8) = o;
    }
  }
}

// ---------------------------------------------------------------------------
// Attention: per (qtile of 64, b, l-split of 2048).
//   S[l 64][q 64] = fkT . hk   (waves = m-strips of 16; hk frags persistent)
//   P = exp(clip(S/8)) -> bf16 -> LDS P_T[q][l] (stride 72)
//   Y[v 64][q 64] += fv . P    (waves = 32x32 quadrants)
// Writes unnormalized Ynum + denom partials; combine kernel divides.
// ---------------------------------------------------------------------------
__global__ __launch_bounds__(256, 2) void attn_kernel(
    const u16* __restrict__ fkT, const u16* __restrict__ hkT,
    const u16* __restrict__ fvp, float* __restrict__ Ynum,
    float* __restrict__ den) {
  constexpr int LL = 4096, DD = 64, SPAD = 72;
  const int tid = threadIdx.x;
  const int w = tid >> 6;
  const int lane = tid & 63;
  const int q15 = lane & 15;
  const int quad = lane >> 4;
  const int qtile = blockIdx.x;
  const int b = blockIdx.y;
  const int split = blockIdx.z;
  const int q0 = qtile * 64;
  const int l0base = split * 2048;

  __shared__ __align__(16) u16 sP[64 * SPAD];
  __shared__ float sDred[4][64];

  // hk B-fragments, persistent in registers: B[k][n=q], n=lane&15, k=quad*8+j
  bf16x8 hkf[4][2];
#pragma unroll
  for (int j = 0; j < 4; ++j)
#pragma unroll
    for (int ks = 0; ks < 2; ++ks)
      hkf[j][ks] = *reinterpret_cast<const bf16x8*>(
          hkT + ((size_t)(b * LL + q0 + j * 16 + q15)) * DD + ks * 32 + quad * 8);

  f32x4 Yacc[2][2];
#pragma unroll
  for (int mm = 0; mm < 2; ++mm)
#pragma unroll
    for (int nn = 0; nn < 2; ++nn) Yacc[mm][nn] = (f32x4){0.f, 0.f, 0.f, 0.f};
  float dsum[4] = {0.f, 0.f, 0.f, 0.f};

  const int m0y = (w & 1) * 32;   // v quadrant
  const int n0y = (w >> 1) * 32;  // q quadrant

  const u16* fkBase =
      fkT + ((size_t)(b * LL + w * 16 + q15)) * DD + quad * 8;

  for (int it = 0; it < 32; ++it) {
    const int l0 = l0base + it * 64;

    // --- S = fk^T . hk for this wave's m-strip (rows w*16..w*16+15) ---
    bf16x8 fkf[2];
#pragma unroll
    for (int ks = 0; ks < 2; ++ks)
      fkf[ks] = *reinterpret_cast<const bf16x8*>(fkBase + (size_t)l0 * DD + ks * 32);

    f32x4 accS[4];
#pragma unroll
    for (int j = 0; j < 4; ++j) accS[j] = (f32x4){0.f, 0.f, 0.f, 0.f};
#pragma unroll
    for (int ks = 0; ks < 2; ++ks)
#pragma unroll
      for (int j = 0; j < 4; ++j) accS[j] = MFMA16(fkf[ks], hkf[j][ks], accS[j]);

    __syncthreads();  // prior PV reads of sP complete

    // --- P = exp(clip(S/8)) -> bf16 -> LDS transposed P_T[q][l] ---
#pragma unroll
    for (int j = 0; j < 4; ++j) {
      bf16x4 pk;
      float ds = 0.f;
#pragma unroll
      for (int r = 0; r < 4; ++r) {
        float zz = accS[j][r] * 0.125f;
        zz = fminf(30.0f, fmaxf(-30.0f, zz));
        float e = __expf(zz);
        __bf16 h = (__bf16)e;
        pk[r] = h;
        ds += (float)h;  // denom consistent with bf16 weights fed to PV
      }
      dsum[j] += ds;
      // C/D layout: col q = j*16+q15, rows l = w*16+quad*4+{0..3} -> b64 write
      *reinterpret_cast<uint32x2*>(&sP[(j * 16 + q15) * SPAD + w * 16 + quad * 4]) =
          __builtin_bit_cast(uint32x2, pk);
    }
    __syncthreads();  // P_T visible to all waves

    // --- Y += fv . P  (wave quadrant m0y x n0y, 32x32) ---
#pragma unroll
    for (int ks = 0; ks < 2; ++ks) {
      bf16x8 af[2], bfr[2];
#pragma unroll
      for (int mm = 0; mm < 2; ++mm)
        af[mm] = *reinterpret_cast<const bf16x8*>(
            fvp + ((size_t)(b * DD + m0y + mm * 16 + q15)) * LL + l0 + ks * 32 + quad * 8);
#pragma unroll
      for (int nn = 0; nn < 2; ++nn)
        bfr[nn] = *reinterpret_cast<const bf16x8*>(
            &sP[(n0y + nn * 16 + q15) * SPAD + ks * 32 + quad * 8]);
#pragma unroll
      for (int mm = 0; mm < 2; ++mm)
#pragma unroll
        for (int nn = 0; nn < 2; ++nn)
          Yacc[mm][nn] = MFMA16(af[mm], bfr[nn], Yacc[mm][nn]);
    }
  }

  // --- denom: reduce across quads (rows of strip), then across waves ---
#pragma unroll
  for (int j = 0; j < 4; ++j) {
    float d = dsum[j];
    d += __shfl_xor(d, 16, 64);
    d += __shfl_xor(d, 32, 64);
    dsum[j] = d;
  }
  if (quad == 0) {
#pragma unroll
    for (int j = 0; j < 4; ++j) sDred[w][j * 16 + q15] = dsum[j];
  }
  __syncthreads();

  const size_t slot = ((size_t)split * 4 + b) * 64 + qtile;
  if (tid < 64) {
    den[slot * 64 + tid] =
        sDred[0][tid] + sDred[1][tid] + sDred[2][tid] + sDred[3][tid];
  }

  float* Yo = Ynum + slot * 4096;
#pragma unroll
  for (int mm = 0; mm < 2; ++mm)
#pragma unroll
    for (int nn = 0; nn < 2; ++nn)
#pragma unroll
      for (int r = 0; r < 4; ++r) {
        const int v = m0y + mm * 16 + quad * 4 + r;
        const int ql = n0y + nn * 16 + q15;
        Yo[v * 64 + ql] = Yacc[mm][nn][r];
      }
}

// ---------------------------------------------------------------------------
// Combine the two l-splits and normalize. out[b][v][q], 1M elements.
// ---------------------------------------------------------------------------
__global__ __launch_bounds__(256) void combine_kernel(
    const float* __restrict__ Yn, const float* __restrict__ dn,
    float* __restrict__ out) {
  const int idx = blockIdx.x * 256 + threadIdx.x;
  const int q = idx & 4095;
  const int v = (idx >> 12) & 63;
  const int b = idx >> 18;
  const int qt = q >> 6, ql = q & 63;
  const size_t s0 = ((size_t)0 * 4 + b) * 64 + qt;
  const size_t s1 = ((size_t)1 * 4 + b) * 64 + qt;
  const float num = Yn[s0 * 4096 + v * 64 + ql] + Yn[s1 * 4096 + v * 64 + ql];
  const float d = dn[s0 * 64 + ql] + dn[s1 * 64 + ql] + 1e-16f;
  out[idx] = num / d;
}

extern "C" void kernel_launch(void* const* d_in, const int* in_sizes, int n_in,
                              void* d_out, int out_size, void* d_ws,
                              size_t ws_size, hipStream_t stream) {
  const float* field = (const float*)d_in[0];
  const float* query = (const float*)d_in[1];
  const float* Wfk = (const float*)d_in[2];
  const float* bfk = (const float*)d_in[3];
  const float* Wfv = (const float*)d_in[4];
  const float* bfv = (const float*)d_in[5];
  const float* Wqk = (const float*)d_in[6];
  const float* bqk = (const float*)d_in[7];
  float* out = (float*)d_out;

  char* ws = (char*)d_ws;
  u16* fkT = (u16*)(ws);                       // 2 MB  [B][L][64] bf16
  u16* hkT = (u16*)(ws + (2ull << 20));        // 2 MB  [B][L][64] bf16
  u16* fvp = (u16*)(ws + (4ull << 20));        // 2 MB  [B][64][L] bf16
  float* Ynum = (float*)(ws + (6ull << 20));   // 8 MB  [2][B][64qt][64v][64q]
  float* den = (float*)(ws + (14ull << 20));   // 128KB [2][B][64qt][64q]

  proj_kernel<<<dim3(16, 4, 6), 256, 0, stream>>>(field, query, Wfk, bfk, Wfv,
                                                  bfv, Wqk, bqk, fkT, fvp, hkT);
  attn_kernel<<<dim3(64, 4, 2), 256, 0, stream>>>(fkT, hkT, fvp, Ynum, den);
  combine_kernel<<<dim3(4096), 256, 0, stream>>>(Ynum, den, out);
}

// Round 2
// 160.757 us; speedup vs baseline: 1.1322x; 1.1322x over previous
//
#include <hip/hip_runtime.h>
#include <hip/hip_bf16.h>

typedef unsigned short u16;
typedef __bf16 bf16x8 __attribute__((ext_vector_type(8)));
typedef __bf16 bf16x4 __attribute__((ext_vector_type(4)));
typedef float f32x4 __attribute__((ext_vector_type(4)));
typedef unsigned int uint32x2 __attribute__((ext_vector_type(2)));

#define MFMA16(a, b, c) __builtin_amdgcn_mfma_f32_16x16x32_bf16(a, b, c, 0, 0, 0)

// exp(z/8) = exp2(z * log2(e)/8); this factor is folded into fkT at proj time.
#define FK_SCALE 0.1803368801111204f  // 0.125 * log2(e)

#define NSPLIT 8

// ---------------------------------------------------------------------------
// Projections: fkeys/fvals/hkeys = W @ src + b, output bf16.
//   fkT[b][l][64]  (k contiguous, PRE-SCALED by FK_SCALE)
//   hkT[b][q][64]  (k contiguous)
//   fv [b][64][l]  (l contiguous)
// grid: (16, B, 12)  z = proj*4 + kquarter  (16 k-rows per block)
// 4 interleaved FMA chains per row-group for ILP.
// ---------------------------------------------------------------------------
__global__ __launch_bounds__(256) void proj_kernel(
    const float* __restrict__ field, const float* __restrict__ query,
    const float* __restrict__ Wfk, const float* __restrict__ bfk,
    const float* __restrict__ Wfv, const float* __restrict__ bfv,
    const float* __restrict__ Wqk, const float* __restrict__ bqk,
    u16* __restrict__ fkT, u16* __restrict__ fvp, u16* __restrict__ hkT) {
  const int l = blockIdx.x * 256 + threadIdx.x;
  const int b = blockIdx.y;
  const int z = blockIdx.z;
  const int proj = z >> 2;        // 0=fk, 1=fv, 2=hk
  const int k0 = (z & 3) * 16;

  const float* src  = (proj == 2) ? query : field;
  const float* W    = (proj == 0) ? Wfk : (proj == 1) ? Wfv : Wqk;
  const float* bias = (proj == 0) ? bfk : (proj == 1) ? bfv : bqk;

  // pull the whole channel column into registers (128 VGPRs)
  float x[128];
  const float* sp = src + (size_t)b * 128 * 4096 + l;
#pragma unroll
  for (int f = 0; f < 128; ++f) x[f] = sp[(size_t)f * 4096];

  float acc[16];
#pragma unroll 1
  for (int i = 0; i < 16; i += 4) {
    const float* wr = W + (size_t)(k0 + i) * 128;
    float a0 = bias[k0 + i + 0];
    float a1 = bias[k0 + i + 1];
    float a2 = bias[k0 + i + 2];
    float a3 = bias[k0 + i + 3];
#pragma unroll
    for (int f = 0; f < 128; ++f) {
      a0 = fmaf(wr[f], x[f], a0);
      a1 = fmaf(wr[128 + f], x[f], a1);
      a2 = fmaf(wr[256 + f], x[f], a2);
      a3 = fmaf(wr[384 + f], x[f], a3);
    }
    acc[i + 0] = a0; acc[i + 1] = a1; acc[i + 2] = a2; acc[i + 3] = a3;
  }

  if (proj == 1) {
#pragma unroll
    for (int i = 0; i < 16; ++i) {
      __bf16 h = (__bf16)acc[i];
      fvp[((size_t)(b * 64 + k0 + i)) * 4096 + l] = __builtin_bit_cast(u16, h);
    }
  } else {
    const float cs = (proj == 0) ? FK_SCALE : 1.0f;
    u16* dst = ((proj == 0) ? fkT : hkT) + ((size_t)(b * 4096 + l)) * 64 + k0;
#pragma unroll
    for (int g = 0; g < 2; ++g) {
      bf16x8 o;
#pragma unroll
      for (int j = 0; j < 8; ++j) o[j] = (__bf16)(acc[g * 8 + j] * cs);
      *reinterpret_cast<bf16x8*>(dst + g * 8) = o;
    }
  }
}

// ---------------------------------------------------------------------------
// Attention: per (qtile of 64, b, l-split of 512).
//   S'[l 64][q 64] = fkT . hk  (scale pre-folded; waves = 16-row m-strips,
//                               hk fragments persistent in registers)
//   P = exp2(S') -> bf16 -> LDS P_T[q][l], XOR-swizzled (conflict-free)
//   Y[v 64][q 64] += fv . P    (waves = 32x32 quadrants)
// Writes unnormalized Ynum + denom partials; combine kernel divides.
// ---------------------------------------------------------------------------
__global__ __launch_bounds__(256, 4) void attn_kernel(
    const u16* __restrict__ fkT, const u16* __restrict__ hkT,
    const u16* __restrict__ fvp, float* __restrict__ Ynum,
    float* __restrict__ den) {
  constexpr int LL = 4096, DD = 64;
  const int tid = threadIdx.x;
  const int w = tid >> 6;
  const int lane = tid & 63;
  const int q15 = lane & 15;
  const int quad = lane >> 4;
  const int qtile = blockIdx.x;
  const int b = blockIdx.y;
  const int split = blockIdx.z;
  const int q0 = qtile * 64;
  const int l0base = split * (LL / NSPLIT);
  const int sw = (q15 & 7) << 1;  // XOR swizzle term (8B-block granularity)

  __shared__ __align__(16) u16 sP[64 * 64];   // P_T[q][l], swizzled
  __shared__ float sDred[4][64];

  // hk B-fragments, persistent: B[k][n=q], n=lane&15, k=quad*8+j
  bf16x8 hkf[4][2];
#pragma unroll
  for (int j = 0; j < 4; ++j)
#pragma unroll
    for (int ks = 0; ks < 2; ++ks)
      hkf[j][ks] = *reinterpret_cast<const bf16x8*>(
          hkT + ((size_t)(b * LL + q0 + j * 16 + q15)) * DD + ks * 32 + quad * 8);

  f32x4 Yacc[2][2];
#pragma unroll
  for (int mm = 0; mm < 2; ++mm)
#pragma unroll
    for (int nn = 0; nn < 2; ++nn) Yacc[mm][nn] = (f32x4){0.f, 0.f, 0.f, 0.f};
  float dsum[4] = {0.f, 0.f, 0.f, 0.f};

  const int m0y = (w & 1) * 32;   // v quadrant
  const int n0y = (w >> 1) * 32;  // q quadrant

  const u16* fkBase = fkT + ((size_t)(b * LL + w * 16 + q15)) * DD + quad * 8;

  for (int it = 0; it < (LL / NSPLIT) / 64; ++it) {
    const int l0 = l0base + it * 64;

    // --- S' = fk^T . hk for this wave's 16-row strip ---
    bf16x8 fkf[2];
#pragma unroll
    for (int ks = 0; ks < 2; ++ks)
      fkf[ks] = *reinterpret_cast<const bf16x8*>(fkBase + (size_t)l0 * DD + ks * 32);

    f32x4 accS[4];
#pragma unroll
    for (int j = 0; j < 4; ++j) accS[j] = (f32x4){0.f, 0.f, 0.f, 0.f};
#pragma unroll
    for (int ks = 0; ks < 2; ++ks)
#pragma unroll
      for (int j = 0; j < 4; ++j) accS[j] = MFMA16(fkf[ks], hkf[j][ks], accS[j]);

    __syncthreads();  // prior PV reads of sP complete

    // --- P = exp2(S') -> bf16 -> LDS transposed, swizzled ---
#pragma unroll
    for (int j = 0; j < 4; ++j) {
      bf16x4 pk;
      float ds = 0.f;
#pragma unroll
      for (int r = 0; r < 4; ++r) {
        float e = __builtin_amdgcn_exp2f(accS[j][r]);
        pk[r] = (__bf16)e;
        ds += e;
      }
      dsum[j] += ds;
      // C/D: col q = j*16+q15, rows l = w*16+quad*4+{0..3}
      const int blk = (w * 4 + quad) ^ sw;
      *reinterpret_cast<uint32x2*>(&sP[(j * 16 + q15) * 64 + blk * 4]) =
          __builtin_bit_cast(uint32x2, pk);
    }
    __syncthreads();  // P_T visible to all waves

    // --- Y += fv . P  (wave quadrant m0y x n0y, 32x32) ---
#pragma unroll
    for (int ks = 0; ks < 2; ++ks) {
      bf16x8 af[2], bfr[2];
#pragma unroll
      for (int mm = 0; mm < 2; ++mm)
        af[mm] = *reinterpret_cast<const bf16x8*>(
            fvp + ((size_t)(b * DD + m0y + mm * 16 + q15)) * LL + l0 + ks * 32 + quad * 8);
#pragma unroll
      for (int nn = 0; nn < 2; ++nn) {
        const int b0 = (ks * 8 + quad * 2) ^ sw;
        bfr[nn] = *reinterpret_cast<const bf16x8*>(
            &sP[(n0y + nn * 16 + q15) * 64 + b0 * 4]);
      }
#pragma unroll
      for (int mm = 0; mm < 2; ++mm)
#pragma unroll
        for (int nn = 0; nn < 2; ++nn)
          Yacc[mm][nn] = MFMA16(af[mm], bfr[nn], Yacc[mm][nn]);
    }
  }

  // --- denom: reduce across quads (strip rows), then across waves ---
#pragma unroll
  for (int j = 0; j < 4; ++j) {
    float d = dsum[j];
    d += __shfl_xor(d, 16, 64);
    d += __shfl_xor(d, 32, 64);
    dsum[j] = d;
  }
  if (quad == 0) {
#pragma unroll
    for (int j = 0; j < 4; ++j) sDred[w][j * 16 + q15] = dsum[j];
  }
  __syncthreads();

  const size_t slot = ((size_t)split * 4 + b) * 64 + qtile;
  if (tid < 64) {
    den[slot * 64 + tid] =
        sDred[0][tid] + sDred[1][tid] + sDred[2][tid] + sDred[3][tid];
  }

  float* Yo = Ynum + slot * 4096;
#pragma unroll
  for (int mm = 0; mm < 2; ++mm)
#pragma unroll
    for (int nn = 0; nn < 2; ++nn)
#pragma unroll
      for (int r = 0; r < 4; ++r) {
        const int v = m0y + mm * 16 + quad * 4 + r;
        const int ql = n0y + nn * 16 + q15;
        Yo[v * 64 + ql] = Yacc[mm][nn][r];
      }
}

// ---------------------------------------------------------------------------
// Combine the NSPLIT l-splits and normalize. out[b][v][q], 1M elements.
// ---------------------------------------------------------------------------
__global__ __launch_bounds__(256) void combine_kernel(
    const float* __restrict__ Yn, const float* __restrict__ dn,
    float* __restrict__ out) {
  const int idx = blockIdx.x * 256 + threadIdx.x;
  const int q = idx & 4095;
  const int v = (idx >> 12) & 63;
  const int b = idx >> 18;
  const int qt = q >> 6, ql = q & 63;
  float num = 0.f, d = 1e-16f;
#pragma unroll
  for (int s = 0; s < NSPLIT; ++s) {
    const size_t slot = ((size_t)s * 4 + b) * 64 + qt;
    num += Yn[slot * 4096 + v * 64 + ql];
    d += dn[slot * 64 + ql];
  }
  out[idx] = num / d;
}

extern "C" void kernel_launch(void* const* d_in, const int* in_sizes, int n_in,
                              void* d_out, int out_size, void* d_ws,
                              size_t ws_size, hipStream_t stream) {
  const float* field = (const float*)d_in[0];
  const float* query = (const float*)d_in[1];
  const float* Wfk = (const float*)d_in[2];
  const float* bfk = (const float*)d_in[3];
  const float* Wfv = (const float*)d_in[4];
  const float* bfv = (const float*)d_in[5];
  const float* Wqk = (const float*)d_in[6];
  const float* bqk = (const float*)d_in[7];
  float* out = (float*)d_out;

  char* ws = (char*)d_ws;
  u16* fkT = (u16*)(ws);                       // 2 MB   [B][L][64] bf16 (scaled)
  u16* hkT = (u16*)(ws + (2ull << 20));        // 2 MB   [B][L][64] bf16
  u16* fvp = (u16*)(ws + (4ull << 20));        // 2 MB   [B][64][L] bf16
  float* Ynum = (float*)(ws + (6ull << 20));   // 32 MB  [8][B][64qt][64v][64q]
  float* den = (float*)(ws + (38ull << 20));   // 512 KB [8][B][64qt][64q]

  proj_kernel<<<dim3(16, 4, 12), 256, 0, stream>>>(field, query, Wfk, bfk, Wfv,
                                                   bfv, Wqk, bqk, fkT, fvp, hkT);
  attn_kernel<<<dim3(64, 4, NSPLIT), 256, 0, stream>>>(fkT, hkT, fvp, Ynum, den);
  combine_kernel<<<dim3(4096), 256, 0, stream>>>(Ynum, den, out);
}